// Round 2
// baseline (598.669 us; speedup 1.0000x reference)
//
#include <hip/hip_runtime.h>
#include <cstdint>
#include <cstddef>

// ---------- types ----------
typedef __bf16 bf16_t;
typedef __bf16 bf16x8 __attribute__((ext_vector_type(8)));
typedef __bf16 bf16x4 __attribute__((ext_vector_type(4)));
typedef float f32x4 __attribute__((ext_vector_type(4)));

// async global->LDS, 16B per lane. LDS dest must be wave-uniform base + lane*16.
#define GL2LDS16(gptr, lptr)                                                   \
  __builtin_amdgcn_global_load_lds(                                            \
      (__attribute__((address_space(1))) void*)(gptr),                         \
      (__attribute__((address_space(3))) void*)(lptr), 16, 0, 0)

// ---------- problem constants ----------
#define BATCH 2
#define T_SEQ 2048
#define NH 16
#define NKV 4
#define HD 128
#define EMB 2048
#define KVDIM (NKV * HD)       // 512
#define MROWS (BATCH * T_SEQ)  // 4096

// =====================================================================
// fp32 -> bf16 conversion (memory-bound, vectorized 16B load / 8B store)
// =====================================================================
__global__ void cvt_f32_bf16(const float4* __restrict__ src,
                             bf16x4* __restrict__ dst, int n4) {
  const int i = blockIdx.x * blockDim.x + threadIdx.x;
  if (i < n4) {
    const float4 v = src[i];
    dst[i] = bf16x4{(__bf16)v.x, (__bf16)v.y, (__bf16)v.z, (__bf16)v.w};
  }
}

// =====================================================================
// GEMM: C(M,N) = A(M,K) @ B(N,K)^T   bf16 inputs, f32 accum, CT output.
// 128x128 tile, BK=64, 256 threads (4 waves, 2x2 of 64x64).
// =====================================================================
template <typename CT>
__global__ __launch_bounds__(256, 2)
void gemm_bt(const bf16_t* __restrict__ A, const bf16_t* __restrict__ Bm,
             CT* __restrict__ C, int M, int N, int K)
{
  __shared__ bf16_t As[128 * 64];
  __shared__ bf16_t Bs[128 * 64];

  const int tid  = threadIdx.x;
  const int lane = tid & 63;
  const int wv   = tid >> 6;
  const int m0 = blockIdx.y * 128;
  const int n0 = blockIdx.x * 128;
  const int wm = (wv >> 1) * 64;
  const int wn = (wv & 1) * 64;
  const int l15 = lane & 15;
  const int lq  = lane >> 4;

  f32x4 acc[4][4] = {};

  const int srow = tid >> 3;        // + r*32
  const int scol = (tid & 7) * 8;

  for (int k0 = 0; k0 < K; k0 += 64) {
#pragma unroll
    for (int r = 0; r < 4; ++r) {
      const int row = r * 32 + srow;
      GL2LDS16(A + (size_t)(m0 + row) * K + k0 + scol, As + row * 64 + scol);
    }
#pragma unroll
    for (int r = 0; r < 4; ++r) {
      const int row = r * 32 + srow;
      GL2LDS16(Bm + (size_t)(n0 + row) * K + k0 + scol, Bs + row * 64 + scol);
    }
    __syncthreads();

#pragma unroll
    for (int ks = 0; ks < 2; ++ks) {
      const int kc = ks * 32 + lq * 8;
      bf16x8 af[4], bf[4];
#pragma unroll
      for (int i = 0; i < 4; ++i)
        af[i] = *(const bf16x8*)(As + (wm + i * 16 + l15) * 64 + kc);
#pragma unroll
      for (int j = 0; j < 4; ++j)
        bf[j] = *(const bf16x8*)(Bs + (wn + j * 16 + l15) * 64 + kc);
#pragma unroll
      for (int i = 0; i < 4; ++i)
#pragma unroll
        for (int j = 0; j < 4; ++j)
          acc[i][j] = __builtin_amdgcn_mfma_f32_16x16x32_bf16(af[i], bf[j], acc[i][j], 0, 0, 0);
    }
    __syncthreads();
  }

  // C/D layout: col = lane&15, row = (lane>>4)*4 + reg
#pragma unroll
  for (int i = 0; i < 4; ++i) {
    const int rbase = m0 + wm + i * 16 + lq * 4;
#pragma unroll
    for (int j = 0; j < 4; ++j) {
      const int col = n0 + wn + j * 16 + l15;
#pragma unroll
      for (int r = 0; r < 4; ++r)
        C[(size_t)(rbase + r) * N + col] = (CT)acc[i][j][r];
    }
  }
}

// =====================================================================
// Flash attention, causal, GQA (h -> h/4).
// Q/Y (B,T,NH,HD), K/V (B,T,NKV,HD), all bf16.
// Block: 256 thr = 4 waves; q-tile of 64 rows (16 per wave); kv tiles of 64.
// =====================================================================
#define VSTR 88   // padded transposed-V row stride (16B aligned)
#define PSTR 88

__global__ __launch_bounds__(256, 2)
void attn_fwd(const bf16_t* __restrict__ Q, const bf16_t* __restrict__ Kg,
              const bf16_t* __restrict__ Vg, bf16_t* __restrict__ Y)
{
  __shared__ bf16_t Ks[64 * 128];        // kv row-major
  __shared__ bf16_t Vs[128 * VSTR];      // transposed: [d][kv]
  __shared__ bf16_t Ps[4][16 * PSTR];    // per-wave P tile

  const int tid  = threadIdx.x;
  const int lane = tid & 63;
  const int wv   = tid >> 6;
  const int l15  = lane & 15;
  const int lq   = lane >> 4;
  const int qt = blockIdx.x;   // 0..31
  const int h  = blockIdx.y;   // 0..15
  const int b  = blockIdx.z;   // 0..1
  const int hkv = h >> 2;
  const int q0 = qt * 64;

  // Q fragments for this wave's 16 rows (A-layout: m=lane&15, k=lq*8+j)
  bf16x8 qf[4];
  {
    const int qrow = q0 + wv * 16 + l15;
    const bf16_t* qp = Q + ((size_t)(b * T_SEQ + qrow) * NH + h) * HD + lq * 8;
#pragma unroll
    for (int ds = 0; ds < 4; ++ds)
      qf[ds] = *(const bf16x8*)(qp + ds * 32);
  }

  float m_s[4], l_s[4];
  f32x4 o[8];
#pragma unroll
  for (int r = 0; r < 4; ++r) { m_s[r] = -1e30f; l_s[r] = 0.f; }
#pragma unroll
  for (int nb = 0; nb < 8; ++nb) o[nb] = f32x4{0.f, 0.f, 0.f, 0.f};

  const float scale = 0.08838834764831845f;  // 1/sqrt(128)
  const int nkt = qt + 1;
  bf16_t* Psw = Ps[wv];
  const int qbase = q0 + wv * 16 + lq * 4;

  for (int kt = 0; kt < nkt; ++kt) {
    // ---- stage K tile (64x128) via global_load_lds ----
    {
      const int col = (tid & 15) * 8;
#pragma unroll
      for (int r = 0; r < 4; ++r) {
        const int row = r * 16 + (tid >> 4);
        GL2LDS16(Kg + ((size_t)(b * T_SEQ + kt * 64 + row) * NKV + hkv) * HD + col,
                 Ks + row * 128 + col);
      }
    }
    // ---- stage V transposed: Vs[d][kv] ----
    {
#pragma unroll
      for (int r = 0; r < 4; ++r) {
        const int c  = r * 256 + tid;
        const int kv = c & 63;
        const int db = (c >> 6) * 8;
        bf16x8 v = *(const bf16x8*)(Vg + ((size_t)(b * T_SEQ + kt * 64 + kv) * NKV + hkv) * HD + db);
#pragma unroll
        for (int j = 0; j < 8; ++j)
          Vs[(db + j) * VSTR + kv] = v[j];
      }
    }
    __syncthreads();

    // ---- S = Q K^T  (16 q-rows x 64 kv-cols per wave) ----
    f32x4 s[4];
#pragma unroll
    for (int nb = 0; nb < 4; ++nb) {
      s[nb] = f32x4{0.f, 0.f, 0.f, 0.f};
#pragma unroll
      for (int ds = 0; ds < 4; ++ds) {
        bf16x8 kf = *(const bf16x8*)(Ks + (nb * 16 + l15) * 128 + ds * 32 + lq * 8);
        s[nb] = __builtin_amdgcn_mfma_f32_16x16x32_bf16(qf[ds], kf, s[nb], 0, 0, 0);
      }
    }

    // ---- online softmax (rows qbase..qbase+3 owned across 16 lanes) ----
#pragma unroll
    for (int r = 0; r < 4; ++r) {
      const int qrow = qbase + r;
      float sv[4];
      float mx = -1e30f;
#pragma unroll
      for (int nb = 0; nb < 4; ++nb) {
        const int kcol = kt * 64 + nb * 16 + l15;
        float v = s[nb][r] * scale;
        v = (kcol <= qrow) ? v : -1e30f;
        sv[nb] = v;
        mx = fmaxf(mx, v);
      }
      mx = fmaxf(mx, __shfl_xor(mx, 1));
      mx = fmaxf(mx, __shfl_xor(mx, 2));
      mx = fmaxf(mx, __shfl_xor(mx, 4));
      mx = fmaxf(mx, __shfl_xor(mx, 8));
      const float mnew = fmaxf(m_s[r], mx);
      const float alpha = __expf(m_s[r] - mnew);
      m_s[r] = mnew;
      float rs = 0.f;
#pragma unroll
      for (int nb = 0; nb < 4; ++nb) {
        const float p = __expf(sv[nb] - mnew);
        rs += p;
        Psw[(lq * 4 + r) * PSTR + nb * 16 + l15] = (bf16_t)p;
      }
      rs += __shfl_xor(rs, 1);
      rs += __shfl_xor(rs, 2);
      rs += __shfl_xor(rs, 4);
      rs += __shfl_xor(rs, 8);
      l_s[r] = l_s[r] * alpha + rs;
#pragma unroll
      for (int nb = 0; nb < 8; ++nb) o[nb][r] *= alpha;
    }

    __builtin_amdgcn_s_waitcnt(0);  // P writes drained before same-wave reads

    // ---- O += P V  (P: A-layout from LDS; V: B-layout from transposed Vs) ----
#pragma unroll
    for (int ks = 0; ks < 2; ++ks) {
      bf16x8 pf = *(const bf16x8*)(Psw + l15 * PSTR + ks * 32 + lq * 8);
#pragma unroll
      for (int nb = 0; nb < 8; ++nb) {
        bf16x8 vf = *(const bf16x8*)(Vs + (nb * 16 + l15) * VSTR + ks * 32 + lq * 8);
        o[nb] = __builtin_amdgcn_mfma_f32_16x16x32_bf16(pf, vf, o[nb], 0, 0, 0);
      }
    }
    __syncthreads();
  }

  // ---- epilogue: normalize and store Y (B,T,NH,HD) ----
  float inv_l[4];
#pragma unroll
  for (int r = 0; r < 4; ++r) inv_l[r] = 1.f / l_s[r];
#pragma unroll
  for (int nb = 0; nb < 8; ++nb) {
    const int dcol = nb * 16 + l15;
#pragma unroll
    for (int r = 0; r < 4; ++r) {
      const int qrow = qbase + r;
      Y[((size_t)(b * T_SEQ + qrow) * NH + h) * HD + dcol] = (bf16_t)(o[nb][r] * inv_l[r]);
    }
  }
}

// =====================================================================
// launch
// =====================================================================
extern "C" void kernel_launch(void* const* d_in, const int* in_sizes, int n_in,
                              void* d_out, int out_size, void* d_ws, size_t ws_size,
                              hipStream_t stream) {
  // Inputs are FLOAT32 per the reference; output is FLOAT32.
  const float* x  = (const float*)d_in[0];
  const float* wq = (const float*)d_in[1];
  const float* wk = (const float*)d_in[2];
  const float* wv = (const float*)d_in[3];
  const float* wo = (const float*)d_in[4];
  float* out = (float*)d_out;

  const size_t n_x  = (size_t)MROWS * EMB;    // 8.4M
  const size_t n_wq = (size_t)EMB * EMB;      // 4.2M
  const size_t n_wk = (size_t)KVDIM * EMB;    // 1.05M
  const size_t n_wv = n_wk;
  const size_t n_wo = n_wq;

  bf16_t* xb  = (bf16_t*)d_ws;
  bf16_t* wqb = xb  + n_x;
  bf16_t* wkb = wqb + n_wq;
  bf16_t* wvb = wkb + n_wk;
  bf16_t* wob = wvb + n_wv;
  bf16_t* Qb  = wob + n_wo;                 // 4096*2048
  bf16_t* Kb  = Qb + (size_t)MROWS * EMB;   // 4096*512
  bf16_t* Vb  = Kb + (size_t)MROWS * KVDIM;
  bf16_t* Yb  = Vb + (size_t)MROWS * KVDIM; // 4096*2048

  dim3 blk(256);

  // fp32 -> bf16 conversions
  cvt_f32_bf16<<<dim3((int)(n_x  / 4 / 256)), blk, 0, stream>>>((const float4*)x,  (bf16x4*)xb,  (int)(n_x  / 4));
  cvt_f32_bf16<<<dim3((int)(n_wq / 4 / 256)), blk, 0, stream>>>((const float4*)wq, (bf16x4*)wqb, (int)(n_wq / 4));
  cvt_f32_bf16<<<dim3((int)(n_wk / 4 / 256)), blk, 0, stream>>>((const float4*)wk, (bf16x4*)wkb, (int)(n_wk / 4));
  cvt_f32_bf16<<<dim3((int)(n_wv / 4 / 256)), blk, 0, stream>>>((const float4*)wv, (bf16x4*)wvb, (int)(n_wv / 4));
  cvt_f32_bf16<<<dim3((int)(n_wo / 4 / 256)), blk, 0, stream>>>((const float4*)wo, (bf16x4*)wob, (int)(n_wo / 4));

  // Q = x @ wq^T   (4096,2048)
  gemm_bt<bf16_t><<<dim3(EMB / 128, MROWS / 128), blk, 0, stream>>>(xb, wqb, Qb, MROWS, EMB, EMB);
  // K = x @ wk^T   (4096,512)
  gemm_bt<bf16_t><<<dim3(KVDIM / 128, MROWS / 128), blk, 0, stream>>>(xb, wkb, Kb, MROWS, KVDIM, EMB);
  // V = x @ wv^T
  gemm_bt<bf16_t><<<dim3(KVDIM / 128, MROWS / 128), blk, 0, stream>>>(xb, wvb, Vb, MROWS, KVDIM, EMB);
  // attention
  attn_fwd<<<dim3(T_SEQ / 64, NH, BATCH), blk, 0, stream>>>(Qb, Kb, Vb, Yb);
  // out = Y @ wo^T  (fp32 output)
  gemm_bt<float><<<dim3(EMB / 128, MROWS / 128), blk, 0, stream>>>(Yb, wob, out, MROWS, EMB, EMB);
}

// Round 3
// 479.444 us; speedup vs baseline: 1.2487x; 1.2487x over previous
//
#include <hip/hip_runtime.h>
#include <cstdint>
#include <cstddef>

// ---------- types ----------
typedef __bf16 bf16_t;
typedef __bf16 bf16x8 __attribute__((ext_vector_type(8)));
typedef __bf16 bf16x4 __attribute__((ext_vector_type(4)));
typedef float f32x4 __attribute__((ext_vector_type(4)));

// async global->LDS, 16B per lane. LDS dest must be wave-uniform base + lane*16.
#define GL2LDS16(gptr, lptr)                                                   \
  __builtin_amdgcn_global_load_lds(                                            \
      (__attribute__((address_space(1))) void*)(gptr),                         \
      (__attribute__((address_space(3))) void*)(lptr), 16, 0, 0)

// ---------- problem constants ----------
#define BATCH 2
#define T_SEQ 2048
#define NH 16
#define NKV 4
#define HD 128
#define EMB 2048
#define KVDIM (NKV * HD)       // 512
#define MROWS (BATCH * T_SEQ)  // 4096

// =====================================================================
// fp32 -> bf16 conversion
// =====================================================================
__global__ void cvt_f32_bf16(const float4* __restrict__ src,
                             bf16x4* __restrict__ dst, int n4) {
  const int i = blockIdx.x * blockDim.x + threadIdx.x;
  if (i < n4) {
    const float4 v = src[i];
    dst[i] = bf16x4{(__bf16)v.x, (__bf16)v.y, (__bf16)v.z, (__bf16)v.w};
  }
}

// =====================================================================
// V transpose: Vb (B*T, 512) -> Vt[(b*512 + dg)][tloc]  (per b: 512x2048)
// 64x64 tiles through LDS, coalesced both sides. Runs once (~4 MB).
// =====================================================================
__global__ __launch_bounds__(256)
void transpose_v(const bf16_t* __restrict__ Vb, bf16_t* __restrict__ Vt) {
  __shared__ bf16_t ts[64][72];   // +8 pad: row stride 144B (16B aligned)
  const int tid = threadIdx.x;
  const int td = blockIdx.x;   // 0..7   d-tile over 512
  const int tt = blockIdx.y;   // 0..63  t-tile over 4096
#pragma unroll
  for (int i = 0; i < 2; ++i) {
    const int c8 = i * 256 + tid;     // 0..511
    const int r  = c8 >> 3;           // 0..63
    const int c  = (c8 & 7) * 8;
    *(bf16x8*)&ts[r][c] =
        *(const bf16x8*)(Vb + ((size_t)(tt * 64 + r)) * KVDIM + td * 64 + c);
  }
  __syncthreads();
  const int b = tt >> 5;
  const int tloc0 = (tt & 31) * 64;
#pragma unroll
  for (int i = 0; i < 2; ++i) {
    const int c8 = i * 256 + tid;
    const int dr = c8 >> 3;           // 0..63
    const int tc = (c8 & 7) * 8;
    bf16x8 v;
#pragma unroll
    for (int j = 0; j < 8; ++j) v[j] = ts[tc + j][dr];
    *(bf16x8*)(Vt + ((size_t)(b * KVDIM + td * 64 + dr)) * T_SEQ + tloc0 + tc) = v;
  }
}

// =====================================================================
// GEMM: C(M,N) = alpha * A(M,K) @ B(N,K)^T   bf16 in, f32 accum, CT out.
// 128x128 tile, BK=64, 256 threads (4 waves, 2x2 of 64x64).  (m97 structure)
// =====================================================================
template <typename CT>
__global__ __launch_bounds__(256, 2)
void gemm_bt(const bf16_t* __restrict__ A, const bf16_t* __restrict__ Bm,
             CT* __restrict__ C, int M, int N, int K, float alpha)
{
  __shared__ bf16_t As[128 * 64];
  __shared__ bf16_t Bs[128 * 64];

  const int tid  = threadIdx.x;
  const int lane = tid & 63;
  const int wv   = tid >> 6;
  const int m0 = blockIdx.y * 128;
  const int n0 = blockIdx.x * 128;
  const int wm = (wv >> 1) * 64;
  const int wn = (wv & 1) * 64;
  const int l15 = lane & 15;
  const int lq  = lane >> 4;

  f32x4 acc[4][4] = {};

  const int srow = tid >> 3;        // + r*32
  const int scol = (tid & 7) * 8;

  for (int k0 = 0; k0 < K; k0 += 64) {
#pragma unroll
    for (int r = 0; r < 4; ++r) {
      const int row = r * 32 + srow;
      GL2LDS16(A + (size_t)(m0 + row) * K + k0 + scol, As + row * 64 + scol);
    }
#pragma unroll
    for (int r = 0; r < 4; ++r) {
      const int row = r * 32 + srow;
      GL2LDS16(Bm + (size_t)(n0 + row) * K + k0 + scol, Bs + row * 64 + scol);
    }
    __syncthreads();

#pragma unroll
    for (int ks = 0; ks < 2; ++ks) {
      const int kc = ks * 32 + lq * 8;
      bf16x8 af[4], bf[4];
#pragma unroll
      for (int i = 0; i < 4; ++i)
        af[i] = *(const bf16x8*)(As + (wm + i * 16 + l15) * 64 + kc);
#pragma unroll
      for (int j = 0; j < 4; ++j)
        bf[j] = *(const bf16x8*)(Bs + (wn + j * 16 + l15) * 64 + kc);
#pragma unroll
      for (int i = 0; i < 4; ++i)
#pragma unroll
        for (int j = 0; j < 4; ++j)
          acc[i][j] = __builtin_amdgcn_mfma_f32_16x16x32_bf16(af[i], bf[j], acc[i][j], 0, 0, 0);
    }
    __syncthreads();
  }

  // C/D layout: col = lane&15, row = (lane>>4)*4 + reg
#pragma unroll
  for (int i = 0; i < 4; ++i) {
    const int rbase = m0 + wm + i * 16 + lq * 4;
#pragma unroll
    for (int j = 0; j < 4; ++j) {
      const int col = n0 + wn + j * 16 + l15;
#pragma unroll
      for (int r = 0; r < 4; ++r)
        C[(size_t)(rbase + r) * N + col] = (CT)(acc[i][j][r] * alpha);
    }
  }
}

// =====================================================================
// Flash attention, causal, GQA (h -> h>>2).
// Q/Y (B,T,NH,HD); K (B,T,NKV,HD); V pre-transposed Vt[(b*512+dg)][t].
// Q is PRE-SCALED by SCALE*log2(e) -> softmax uses exp2.
// Block: 256 thr = 4 waves; q-tile 64 (16 rows/wave); kv tile 64.
// Double-buffered K/V staging, single barrier per iteration.
// K/V LDS layout is XOR-swizzled by (row&7) in 16B blocks -> 2-way banks.
// =====================================================================
#define PSTR 72   // 36 words == 4 mod 32 -> 2-way on A-frag reads

__global__ __launch_bounds__(256, 2)
void attn_fwd(const bf16_t* __restrict__ Q, const bf16_t* __restrict__ Kg,
              const bf16_t* __restrict__ Vt, bf16_t* __restrict__ Y)
{
  __shared__ bf16_t Ks[2][64 * 128];   // [row t 0..63][pos 0..15 of 16B], pos = blk ^ (row&7)
  __shared__ bf16_t Vs[2][128 * 64];   // [row d 0..127][pos 0..7  of 16B], pos = blk ^ (row&7)
  __shared__ bf16_t Ps[4][16 * PSTR];  // per-wave P tile

  const int tid  = threadIdx.x;
  const int lane = tid & 63;
  const int wv   = tid >> 6;
  const int l15  = lane & 15;
  const int lq   = lane >> 4;
  const int qt = (gridDim.x - 1) - blockIdx.x;  // heavy blocks first
  const int h  = blockIdx.y;
  const int b  = blockIdx.z;
  const int hkv = h >> 2;
  const int q0 = qt * 64;

  // Q fragments (A-layout: m=lane&15, k=lq*8+j). Q already scaled.
  bf16x8 qf[4];
  {
    const int qrow = q0 + wv * 16 + l15;
    const bf16_t* qp = Q + ((size_t)(b * T_SEQ + qrow) * NH + h) * HD + lq * 8;
#pragma unroll
    for (int ds = 0; ds < 4; ++ds)
      qf[ds] = *(const bf16x8*)(qp + ds * 32);
  }

  float m_s[4], l_s[4];
  f32x4 o[8];
#pragma unroll
  for (int r = 0; r < 4; ++r) { m_s[r] = -1e30f; l_s[r] = 0.f; }
#pragma unroll
  for (int nb = 0; nb < 8; ++nb) o[nb] = f32x4{0.f, 0.f, 0.f, 0.f};

  const int nkt = qt + 1;
  bf16_t* Psw = Ps[wv];
  const int qbase = q0 + wv * 16 + lq * 4;

  auto stage = [&](int kt, int bufsel) {
    const int base_t = b * T_SEQ + kt * 64;
    // K tile: 64 rows x 128 d (16 blocks of 16B per row)
#pragma unroll
    for (int r = 0; r < 4; ++r) {
      const int c = r * 256 + tid;      // 0..1023
      const int row = c >> 4, p = c & 15;
      const int sb = p ^ (row & 7);
      GL2LDS16(Kg + (size_t)(base_t + row) * KVDIM + hkv * HD + sb * 8,
               &Ks[bufsel][c * 8]);
    }
    // V^T tile: 128 rows (d) x 64 kv (8 blocks of 16B per row)
#pragma unroll
    for (int r = 0; r < 4; ++r) {
      const int c = r * 256 + tid;      // 0..1023
      const int row = c >> 3, p = c & 7;
      const int sb = p ^ (row & 7);
      GL2LDS16(Vt + (size_t)(b * KVDIM + hkv * HD + row) * T_SEQ + kt * 64 + sb * 8,
               &Vs[bufsel][c * 8]);
    }
  };

  stage(0, 0);

  for (int kt = 0; kt < nkt; ++kt) {
    const int cur = kt & 1;
    __syncthreads();                       // stage(kt) complete; buffers safe
    if (kt + 1 < nkt) stage(kt + 1, cur ^ 1);

    // ---- S = Q K^T ----
    f32x4 s[4];
#pragma unroll
    for (int nb = 0; nb < 4; ++nb) {
      s[nb] = f32x4{0.f, 0.f, 0.f, 0.f};
      const int row = nb * 16 + l15;
      const int r7  = row & 7;
#pragma unroll
      for (int ds = 0; ds < 4; ++ds) {
        const bf16x8 kf = *(const bf16x8*)&Ks[cur][row * 128 + (((ds * 4 + lq) ^ r7) * 8)];
        s[nb] = __builtin_amdgcn_mfma_f32_16x16x32_bf16(qf[ds], kf, s[nb], 0, 0, 0);
      }
    }

    // ---- online softmax (base-2; Q pre-scaled by SCALE*log2e) ----
    const bool dia = (kt == nkt - 1);      // only the diagonal tile needs mask
#pragma unroll
    for (int r = 0; r < 4; ++r) {
      float sv[4];
      float mx = -1e30f;
      if (dia) {
        const int qrow = qbase + r;
#pragma unroll
        for (int nb = 0; nb < 4; ++nb) {
          const int kcol = kt * 64 + nb * 16 + l15;
          float v = s[nb][r];
          v = (kcol <= qrow) ? v : -1e30f;
          sv[nb] = v;
          mx = fmaxf(mx, v);
        }
      } else {
#pragma unroll
        for (int nb = 0; nb < 4; ++nb) {
          sv[nb] = s[nb][r];
          mx = fmaxf(mx, sv[nb]);
        }
      }
      mx = fmaxf(mx, __shfl_xor(mx, 1));
      mx = fmaxf(mx, __shfl_xor(mx, 2));
      mx = fmaxf(mx, __shfl_xor(mx, 4));
      mx = fmaxf(mx, __shfl_xor(mx, 8));
      const float mnew = fmaxf(m_s[r], mx);
      const float alpha = exp2f(m_s[r] - mnew);
      m_s[r] = mnew;
      float rs = 0.f;
#pragma unroll
      for (int nb = 0; nb < 4; ++nb) {
        const float p = exp2f(sv[nb] - mnew);
        rs += p;
        Psw[(lq * 4 + r) * PSTR + nb * 16 + l15] = (bf16_t)p;
      }
      rs += __shfl_xor(rs, 1);
      rs += __shfl_xor(rs, 2);
      rs += __shfl_xor(rs, 4);
      rs += __shfl_xor(rs, 8);
      l_s[r] = l_s[r] * alpha + rs;
#pragma unroll
      for (int nb = 0; nb < 8; ++nb) o[nb][r] *= alpha;
    }

    // wait ONLY LDS (keep K/V prefetch in flight!)
    asm volatile("s_waitcnt lgkmcnt(0)" ::: "memory");

    // ---- O += P V ----
#pragma unroll
    for (int ks = 0; ks < 2; ++ks) {
      const bf16x8 pf = *(const bf16x8*)(Psw + l15 * PSTR + ks * 32 + lq * 8);
#pragma unroll
      for (int nb = 0; nb < 8; ++nb) {
        const int row = nb * 16 + l15;
        const bf16x8 vf = *(const bf16x8*)&Vs[cur][row * 64 + (((ks * 4 + lq) ^ (row & 7)) * 8)];
        o[nb] = __builtin_amdgcn_mfma_f32_16x16x32_bf16(pf, vf, o[nb], 0, 0, 0);
      }
    }
  }

  // ---- epilogue ----
  float inv_l[4];
#pragma unroll
  for (int r = 0; r < 4; ++r) inv_l[r] = 1.f / l_s[r];
#pragma unroll
  for (int nb = 0; nb < 8; ++nb) {
    const int dcol = nb * 16 + l15;
#pragma unroll
    for (int r = 0; r < 4; ++r) {
      const int qrow = qbase + r;
      Y[((size_t)(b * T_SEQ + qrow) * NH + h) * HD + dcol] = (bf16_t)(o[nb][r] * inv_l[r]);
    }
  }
}

// =====================================================================
// launch
// =====================================================================
extern "C" void kernel_launch(void* const* d_in, const int* in_sizes, int n_in,
                              void* d_out, int out_size, void* d_ws, size_t ws_size,
                              hipStream_t stream) {
  const float* x  = (const float*)d_in[0];
  const float* wq = (const float*)d_in[1];
  const float* wk = (const float*)d_in[2];
  const float* wv = (const float*)d_in[3];
  const float* wo = (const float*)d_in[4];
  float* out = (float*)d_out;

  const size_t n_x  = (size_t)MROWS * EMB;
  const size_t n_wq = (size_t)EMB * EMB;
  const size_t n_wk = (size_t)KVDIM * EMB;
  const size_t n_wv = n_wk;
  const size_t n_wo = n_wq;

  bf16_t* xb  = (bf16_t*)d_ws;
  bf16_t* wqb = xb  + n_x;
  bf16_t* wkb = wqb + n_wq;
  bf16_t* wvb = wkb + n_wk;
  bf16_t* wob = wvb + n_wv;
  bf16_t* Qb  = wob + n_wo;                  // 4096*2048
  bf16_t* Kb  = Qb + (size_t)MROWS * EMB;    // 4096*512
  bf16_t* Vb  = Kb + (size_t)MROWS * KVDIM;  // 4096*512
  bf16_t* Vtb = Vb + (size_t)MROWS * KVDIM;  // 1024*2048 (transposed V)
  bf16_t* Yb  = Vtb + (size_t)MROWS * KVDIM; // 4096*2048

  dim3 blk(256);

  // fp32 -> bf16
  cvt_f32_bf16<<<dim3((int)(n_x  / 4 / 256)), blk, 0, stream>>>((const float4*)x,  (bf16x4*)xb,  (int)(n_x  / 4));
  cvt_f32_bf16<<<dim3((int)(n_wq / 4 / 256)), blk, 0, stream>>>((const float4*)wq, (bf16x4*)wqb, (int)(n_wq / 4));
  cvt_f32_bf16<<<dim3((int)(n_wk / 4 / 256)), blk, 0, stream>>>((const float4*)wk, (bf16x4*)wkb, (int)(n_wk / 4));
  cvt_f32_bf16<<<dim3((int)(n_wv / 4 / 256)), blk, 0, stream>>>((const float4*)wv, (bf16x4*)wvb, (int)(n_wv / 4));
  cvt_f32_bf16<<<dim3((int)(n_wo / 4 / 256)), blk, 0, stream>>>((const float4*)wo, (bf16x4*)wob, (int)(n_wo / 4));

  // Q = (x @ wq^T) * SCALE*log2e   (folded for exp2 softmax)
  const float qalpha = 0.08838834764831845f * 1.4426950408889634f;
  gemm_bt<bf16_t><<<dim3(EMB / 128, MROWS / 128), blk, 0, stream>>>(xb, wqb, Qb, MROWS, EMB, EMB, qalpha);
  // K = x @ wk^T
  gemm_bt<bf16_t><<<dim3(KVDIM / 128, MROWS / 128), blk, 0, stream>>>(xb, wkb, Kb, MROWS, KVDIM, EMB, 1.0f);
  // V = x @ wv^T, then transpose to Vt
  gemm_bt<bf16_t><<<dim3(KVDIM / 128, MROWS / 128), blk, 0, stream>>>(xb, wvb, Vb, MROWS, KVDIM, EMB, 1.0f);
  transpose_v<<<dim3(KVDIM / 64, MROWS / 64), blk, 0, stream>>>(Vb, Vtb);
  // attention
  attn_fwd<<<dim3(T_SEQ / 64, NH, BATCH), blk, 0, stream>>>(Qb, Kb, Vtb, Yb);
  // out = Y @ wo^T  (fp32 out)
  gemm_bt<float><<<dim3(EMB / 128, MROWS / 128), blk, 0, stream>>>(Yb, wob, out, MROWS, EMB, EMB, 1.0f);
}

// Round 4
// 353.572 us; speedup vs baseline: 1.6932x; 1.3560x over previous
//
#include <hip/hip_runtime.h>
#include <cstdint>
#include <cstddef>

// ---------- types ----------
typedef __bf16 bf16_t;
typedef __bf16 bf16x8 __attribute__((ext_vector_type(8)));
typedef __bf16 bf16x4 __attribute__((ext_vector_type(4)));
typedef float f32x4 __attribute__((ext_vector_type(4)));

// async global->LDS, 16B per lane. LDS dest must be wave-uniform base + lane*16.
#define GL2LDS16(gptr, lptr)                                                   \
  __builtin_amdgcn_global_load_lds(                                            \
      (__attribute__((address_space(1))) void*)(gptr),                         \
      (__attribute__((address_space(3))) void*)(lptr), 16, 0, 0)

// fast 2^x (hardware transcendental; inputs bounded here, masked -> -1e30 -> 0)
__device__ __forceinline__ float fast_exp2(float x) {
  float r;
  asm volatile("v_exp_f32 %0, %1" : "=v"(r) : "v"(x));
  return r;
}

// ---------- problem constants ----------
#define BATCH 2
#define T_SEQ 2048
#define NH 16
#define NKV 4
#define HD 128
#define EMB 2048
#define KVDIM (NKV * HD)       // 512
#define MROWS (BATCH * T_SEQ)  // 4096

// =====================================================================
// fused fp32 -> bf16 conversion for all 5 inputs (one dispatch)
// block ranges: x 8192 | wq 4096 | wk 1024 | wv 1024 | wo 4096 = 18432
// =====================================================================
__global__ void cvt_all(const float4* __restrict__ x,  const float4* __restrict__ wq,
                        const float4* __restrict__ wk, const float4* __restrict__ wv,
                        const float4* __restrict__ wo,
                        bf16x4* __restrict__ xb,  bf16x4* __restrict__ wqb,
                        bf16x4* __restrict__ wkb, bf16x4* __restrict__ wvb,
                        bf16x4* __restrict__ wob) {
  const int blk = blockIdx.x;
  const float4* src;
  bf16x4* dst;
  int base;
  if (blk < 8192)       { src = x;  dst = xb;  base = blk; }
  else if (blk < 12288) { src = wq; dst = wqb; base = blk - 8192; }
  else if (blk < 13312) { src = wk; dst = wkb; base = blk - 12288; }
  else if (blk < 14336) { src = wv; dst = wvb; base = blk - 13312; }
  else                  { src = wo; dst = wob; base = blk - 14336; }
  const int i = base * 256 + threadIdx.x;
  const float4 v = src[i];
  dst[i] = bf16x4{(__bf16)v.x, (__bf16)v.y, (__bf16)v.z, (__bf16)v.w};
}

// =====================================================================
// V transpose: Vb (B*T, 512) -> Vt[(b*512 + dg)][tloc]  (per b: 512x2048)
// =====================================================================
__global__ __launch_bounds__(256)
void transpose_v(const bf16_t* __restrict__ Vb, bf16_t* __restrict__ Vt) {
  __shared__ bf16_t ts[64][72];
  const int tid = threadIdx.x;
  const int td = blockIdx.x;   // 0..7   d-tile over 512
  const int tt = blockIdx.y;   // 0..63  t-tile over 4096
#pragma unroll
  for (int i = 0; i < 2; ++i) {
    const int c8 = i * 256 + tid;
    const int r  = c8 >> 3;
    const int c  = (c8 & 7) * 8;
    *(bf16x8*)&ts[r][c] =
        *(const bf16x8*)(Vb + ((size_t)(tt * 64 + r)) * KVDIM + td * 64 + c);
  }
  __syncthreads();
  const int b = tt >> 5;
  const int tloc0 = (tt & 31) * 64;
#pragma unroll
  for (int i = 0; i < 2; ++i) {
    const int c8 = i * 256 + tid;
    const int dr = c8 >> 3;
    const int tc = (c8 & 7) * 8;
    bf16x8 v;
#pragma unroll
    for (int j = 0; j < 8; ++j) v[j] = ts[tc + j][dr];
    *(bf16x8*)(Vt + ((size_t)(b * KVDIM + td * 64 + dr)) * T_SEQ + tloc0 + tc) = v;
  }
}

// =====================================================================
// GEMM: C(M,N) = alpha * A(M,K) @ B(N,K)^T   bf16 in, f32 accum, CT out.
// 128x128 tile, BK=64, 256 threads (4 waves, 2x2 of 64x64).  (m97 structure)
// =====================================================================
template <typename CT>
__global__ __launch_bounds__(256, 2)
void gemm_bt(const bf16_t* __restrict__ A, const bf16_t* __restrict__ Bm,
             CT* __restrict__ C, int M, int N, int K, float alpha)
{
  __shared__ bf16_t As[128 * 64];
  __shared__ bf16_t Bs[128 * 64];

  const int tid  = threadIdx.x;
  const int lane = tid & 63;
  const int wv   = tid >> 6;
  const int m0 = blockIdx.y * 128;
  const int n0 = blockIdx.x * 128;
  const int wm = (wv >> 1) * 64;
  const int wn = (wv & 1) * 64;
  const int l15 = lane & 15;
  const int lq  = lane >> 4;

  f32x4 acc[4][4] = {};

  const int srow = tid >> 3;
  const int scol = (tid & 7) * 8;

  for (int k0 = 0; k0 < K; k0 += 64) {
#pragma unroll
    for (int r = 0; r < 4; ++r) {
      const int row = r * 32 + srow;
      GL2LDS16(A + (size_t)(m0 + row) * K + k0 + scol, As + row * 64 + scol);
    }
#pragma unroll
    for (int r = 0; r < 4; ++r) {
      const int row = r * 32 + srow;
      GL2LDS16(Bm + (size_t)(n0 + row) * K + k0 + scol, Bs + row * 64 + scol);
    }
    __syncthreads();

#pragma unroll
    for (int ks = 0; ks < 2; ++ks) {
      const int kc = ks * 32 + lq * 8;
      bf16x8 af[4], bf[4];
#pragma unroll
      for (int i = 0; i < 4; ++i)
        af[i] = *(const bf16x8*)(As + (wm + i * 16 + l15) * 64 + kc);
#pragma unroll
      for (int j = 0; j < 4; ++j)
        bf[j] = *(const bf16x8*)(Bs + (wn + j * 16 + l15) * 64 + kc);
#pragma unroll
      for (int i = 0; i < 4; ++i)
#pragma unroll
        for (int j = 0; j < 4; ++j)
          acc[i][j] = __builtin_amdgcn_mfma_f32_16x16x32_bf16(af[i], bf[j], acc[i][j], 0, 0, 0);
    }
    __syncthreads();
  }

  // C/D layout: col = lane&15, row = (lane>>4)*4 + reg
#pragma unroll
  for (int i = 0; i < 4; ++i) {
    const int rbase = m0 + wm + i * 16 + lq * 4;
#pragma unroll
    for (int j = 0; j < 4; ++j) {
      const int col = n0 + wn + j * 16 + l15;
#pragma unroll
      for (int r = 0; r < 4; ++r)
        C[(size_t)(rbase + r) * N + col] = (CT)(acc[i][j][r] * alpha);
    }
  }
}

// =====================================================================
// Flash attention, causal, GQA, NO-MAX softmax (scores bounded; exact
// softmax is shift-invariant), S^T orientation for cheap P transpose.
// Q/Y (B,T,NH,HD); K (B,T,NKV,HD); Vt[(b*512+dg)][t]. Q pre-scaled by
// SCALE*log2e. Grid (16,NH,B): block x does qt=31-x then qt=x (33 iters
// each -> perfect balance, 512 blocks = exactly 2/CU).
// =====================================================================
#define PSTR 72   // row stride (elements); 144 B = 16B-aligned

__global__ __launch_bounds__(256, 2)
void attn_fwd(const bf16_t* __restrict__ Q, const bf16_t* __restrict__ Kg,
              const bf16_t* __restrict__ Vt, bf16_t* __restrict__ Y)
{
  __shared__ bf16_t Ks[2][64 * 128];   // [t 0..63][16B blk], blk = pos ^ (row&7)
  __shared__ bf16_t Vs[2][128 * 64];   // [d 0..127][16B blk], blk = pos ^ (row&7)
  __shared__ bf16_t Ps[4][16 * PSTR];  // per-wave P[q 0..15][kv 0..63]

  const int tid  = threadIdx.x;
  const int lane = tid & 63;
  const int wv   = tid >> 6;
  const int l15  = lane & 15;
  const int lq   = lane >> 4;
  const int h  = blockIdx.y;
  const int b  = blockIdx.z;
  const int hkv = h >> 2;
  bf16_t* Psw = Ps[wv];

  auto stage = [&](int kt, int bufsel) {
    const int base_t = b * T_SEQ + kt * 64;
#pragma unroll
    for (int r = 0; r < 4; ++r) {
      const int c = r * 256 + tid;
      const int row = c >> 4, p = c & 15;
      const int sb = p ^ (row & 7);
      GL2LDS16(Kg + (size_t)(base_t + row) * KVDIM + hkv * HD + sb * 8,
               &Ks[bufsel][c * 8]);
    }
#pragma unroll
    for (int r = 0; r < 4; ++r) {
      const int c = r * 256 + tid;
      const int row = c >> 3, p = c & 7;
      const int sb = p ^ (row & 7);
      GL2LDS16(Vt + (size_t)(b * KVDIM + hkv * HD + row) * T_SEQ + kt * 64 + sb * 8,
               &Vs[bufsel][c * 8]);
    }
  };

#pragma unroll 1
  for (int ph = 0; ph < 2; ++ph) {
    const int qt = ph ? blockIdx.x : (31 - blockIdx.x);
    const int q0 = qt * 64;
    const int nkt = qt + 1;
    const int qabs = q0 + wv * 16 + l15;   // this lane's q row (fixed!)

    // Q fragments (B-operand: n=l15=q, k=lq*8+j consecutive d)
    bf16x8 qf[4];
    {
      const bf16_t* qp = Q + ((size_t)(b * T_SEQ + qabs) * NH + h) * HD + lq * 8;
#pragma unroll
      for (int ds = 0; ds < 4; ++ds)
        qf[ds] = *(const bf16x8*)(qp + ds * 32);
    }

    float l_part = 0.f;
    f32x4 o[8];
#pragma unroll
    for (int nb = 0; nb < 8; ++nb) o[nb] = f32x4{0.f, 0.f, 0.f, 0.f};

    __syncthreads();            // prior phase done reading buffers
    stage(0, 0);

    for (int kt = 0; kt < nkt; ++kt) {
      const int cur = kt & 1;
      __syncthreads();          // stage(kt) complete
      if (kt + 1 < nkt) stage(kt + 1, cur ^ 1);

      // ---- S^T = K Q^T : D[kv][q], lane: q=l15, kv=nb*16+lq*4+r ----
      f32x4 s[4];
#pragma unroll
      for (int nb = 0; nb < 4; ++nb) {
        s[nb] = f32x4{0.f, 0.f, 0.f, 0.f};
        const int row = nb * 16 + l15;
        const int r7  = row & 7;
#pragma unroll
        for (int ds = 0; ds < 4; ++ds) {
          const bf16x8 kf = *(const bf16x8*)&Ks[cur][row * 128 + (((ds * 4 + lq) ^ r7) * 8)];
          s[nb] = __builtin_amdgcn_mfma_f32_16x16x32_bf16(kf, qf[ds], s[nb], 0, 0, 0);
        }
      }

      // ---- p = exp2(s) raw (no max), mask only on diagonal tile ----
      const bool dia = (kt == nkt - 1);
#pragma unroll
      for (int nb = 0; nb < 4; ++nb) {
        const int kvb = kt * 64 + nb * 16 + lq * 4;
        float p0, p1, p2, p3;
        if (dia) {
          p0 = (kvb + 0 <= qabs) ? fast_exp2(s[nb][0]) : 0.f;
          p1 = (kvb + 1 <= qabs) ? fast_exp2(s[nb][1]) : 0.f;
          p2 = (kvb + 2 <= qabs) ? fast_exp2(s[nb][2]) : 0.f;
          p3 = (kvb + 3 <= qabs) ? fast_exp2(s[nb][3]) : 0.f;
        } else {
          p0 = fast_exp2(s[nb][0]);
          p1 = fast_exp2(s[nb][1]);
          p2 = fast_exp2(s[nb][2]);
          p3 = fast_exp2(s[nb][3]);
        }
        l_part += (p0 + p1) + (p2 + p3);
        *(bf16x4*)(Psw + l15 * PSTR + nb * 16 + lq * 4) =
            bf16x4{(__bf16)p0, (__bf16)p1, (__bf16)p2, (__bf16)p3};
      }

      // wait ONLY LDS (keep K/V prefetch in flight)
      asm volatile("s_waitcnt lgkmcnt(0)" ::: "memory");

      // ---- O^T += V^T P^T : D[d][q], lane: q=l15, d=nb*16+lq*4+r ----
#pragma unroll
      for (int ks = 0; ks < 2; ++ks) {
        const bf16x8 pf = *(const bf16x8*)(Psw + l15 * PSTR + ks * 32 + lq * 8);
#pragma unroll
        for (int nb = 0; nb < 8; ++nb) {
          const int row = nb * 16 + l15;
          const bf16x8 vf = *(const bf16x8*)&Vs[cur][row * 64 + (((ks * 4 + lq) ^ (row & 7)) * 8)];
          o[nb] = __builtin_amdgcn_mfma_f32_16x16x32_bf16(vf, pf, o[nb], 0, 0, 0);
        }
      }
    }

    // ---- epilogue: reduce l over lq-group (lanes l15+16*lq), store ----
    float lt = l_part;
    lt += __shfl_xor(lt, 16);
    lt += __shfl_xor(lt, 32);
    const float inv = 1.f / lt;
    bf16_t* yp = Y + ((size_t)(b * T_SEQ + qabs) * NH + h) * HD + lq * 4;
#pragma unroll
    for (int nb = 0; nb < 8; ++nb) {
      *(bf16x4*)(yp + nb * 16) = bf16x4{(__bf16)(o[nb][0] * inv), (__bf16)(o[nb][1] * inv),
                                        (__bf16)(o[nb][2] * inv), (__bf16)(o[nb][3] * inv)};
    }
  }
}

// =====================================================================
// launch
// =====================================================================
extern "C" void kernel_launch(void* const* d_in, const int* in_sizes, int n_in,
                              void* d_out, int out_size, void* d_ws, size_t ws_size,
                              hipStream_t stream) {
  const float* x  = (const float*)d_in[0];
  const float* wq = (const float*)d_in[1];
  const float* wk = (const float*)d_in[2];
  const float* wv = (const float*)d_in[3];
  const float* wo = (const float*)d_in[4];
  float* out = (float*)d_out;

  const size_t n_x  = (size_t)MROWS * EMB;
  const size_t n_wq = (size_t)EMB * EMB;
  const size_t n_wk = (size_t)KVDIM * EMB;
  const size_t n_wv = n_wk;
  const size_t n_wo = n_wq;

  bf16_t* xb  = (bf16_t*)d_ws;
  bf16_t* wqb = xb  + n_x;
  bf16_t* wkb = wqb + n_wq;
  bf16_t* wvb = wkb + n_wk;
  bf16_t* wob = wvb + n_wv;
  bf16_t* Qb  = wob + n_wo;
  bf16_t* Kb  = Qb + (size_t)MROWS * EMB;
  bf16_t* Vb  = Kb + (size_t)MROWS * KVDIM;
  bf16_t* Vtb = Vb + (size_t)MROWS * KVDIM;
  bf16_t* Yb  = Vtb + (size_t)MROWS * KVDIM;

  dim3 blk(256);

  cvt_all<<<dim3(18432), blk, 0, stream>>>(
      (const float4*)x, (const float4*)wq, (const float4*)wk, (const float4*)wv, (const float4*)wo,
      (bf16x4*)xb, (bf16x4*)wqb, (bf16x4*)wkb, (bf16x4*)wvb, (bf16x4*)wob);

  // Q = (x @ wq^T) * SCALE*log2e   (folded for exp2 softmax)
  const float qalpha = 0.08838834764831845f * 1.4426950408889634f;
  gemm_bt<bf16_t><<<dim3(EMB / 128, MROWS / 128), blk, 0, stream>>>(xb, wqb, Qb, MROWS, EMB, EMB, qalpha);
  gemm_bt<bf16_t><<<dim3(KVDIM / 128, MROWS / 128), blk, 0, stream>>>(xb, wkb, Kb, MROWS, KVDIM, EMB, 1.0f);
  gemm_bt<bf16_t><<<dim3(KVDIM / 128, MROWS / 128), blk, 0, stream>>>(xb, wvb, Vb, MROWS, KVDIM, EMB, 1.0f);
  transpose_v<<<dim3(KVDIM / 64, MROWS / 64), blk, 0, stream>>>(Vb, Vtb);
  attn_fwd<<<dim3(16, NH, BATCH), blk, 0, stream>>>(Qb, Kb, Vtb, Yb);
  gemm_bt<float><<<dim3(EMB / 128, MROWS / 128), blk, 0, stream>>>(Yb, wob, out, MROWS, EMB, EMB, 1.0f);
}

// Round 5
// 337.563 us; speedup vs baseline: 1.7735x; 1.0474x over previous
//
#include <hip/hip_runtime.h>
#include <cstdint>
#include <cstddef>

// ---------- types ----------
typedef __bf16 bf16_t;
typedef __bf16 bf16x8 __attribute__((ext_vector_type(8)));
typedef __bf16 bf16x4 __attribute__((ext_vector_type(4)));
typedef float f32x4 __attribute__((ext_vector_type(4)));

// async global->LDS, 16B per lane. LDS dest must be wave-uniform base + lane*16.
#define GL2LDS16(gptr, lptr)                                                   \
  __builtin_amdgcn_global_load_lds(                                            \
      (__attribute__((address_space(1))) void*)(gptr),                         \
      (__attribute__((address_space(3))) void*)(lptr), 16, 0, 0)

// fast 2^x (hardware transcendental; inputs bounded here)
__device__ __forceinline__ float fast_exp2(float x) {
  float r;
  asm volatile("v_exp_f32 %0, %1" : "=v"(r) : "v"(x));
  return r;
}

// ---------- problem constants ----------
#define BATCH 2
#define T_SEQ 2048
#define NH 16
#define NKV 4
#define HD 128
#define EMB 2048
#define KVDIM (NKV * HD)       // 512
#define MROWS (BATCH * T_SEQ)  // 4096

// =====================================================================
// fused fp32 -> bf16 conversion for all 5 inputs (one dispatch)
// block ranges: x 8192 | wq 4096 | wk 1024 | wv 1024 | wo 4096 = 18432
// =====================================================================
__global__ void cvt_all(const float4* __restrict__ x,  const float4* __restrict__ wq,
                        const float4* __restrict__ wk, const float4* __restrict__ wv,
                        const float4* __restrict__ wo,
                        bf16x4* __restrict__ xb,  bf16x4* __restrict__ wqb,
                        bf16x4* __restrict__ wkb, bf16x4* __restrict__ wvb,
                        bf16x4* __restrict__ wob) {
  const int blk = blockIdx.x;
  const float4* src;
  bf16x4* dst;
  int base;
  if (blk < 8192)       { src = x;  dst = xb;  base = blk; }
  else if (blk < 12288) { src = wq; dst = wqb; base = blk - 8192; }
  else if (blk < 13312) { src = wk; dst = wkb; base = blk - 12288; }
  else if (blk < 14336) { src = wv; dst = wvb; base = blk - 13312; }
  else                  { src = wo; dst = wob; base = blk - 14336; }
  const int i = base * 256 + threadIdx.x;
  const float4 v = src[i];
  dst[i] = bf16x4{(__bf16)v.x, (__bf16)v.y, (__bf16)v.z, (__bf16)v.w};
}

// =====================================================================
// Fused QKV GEMM: A = xb (4096 x 2048).  N-blocks (blockIdx.x, 24 total):
//   [0,16):  Q = alpha * x@wq^T  -> Qb (4096x2048)
//   [16,20): K = x@wk^T          -> Kb (4096x512)
//   [20,24): V = x@wv^T          -> Vt TRANSPOSED: Vt[(b*512+d)*2048 + t]
// 128x128 tile, BK=64, 256 threads (4 waves, 2x2 of 64x64). m97 structure.
// =====================================================================
__global__ __launch_bounds__(256, 2)
void gemm_qkv(const bf16_t* __restrict__ A,
              const bf16_t* __restrict__ Wq, const bf16_t* __restrict__ Wk,
              const bf16_t* __restrict__ Wv,
              bf16_t* __restrict__ Qb, bf16_t* __restrict__ Kb,
              bf16_t* __restrict__ Vt, float qalpha)
{
  __shared__ bf16_t As[128 * 64];
  __shared__ bf16_t Bs[128 * 64];

  const int tid  = threadIdx.x;
  const int lane = tid & 63;
  const int wv   = tid >> 6;
  const int nbx = blockIdx.x;
  const int m0 = blockIdx.y * 128;
  const int wm = (wv >> 1) * 64;
  const int wn = (wv & 1) * 64;
  const int l15 = lane & 15;
  const int lq  = lane >> 4;

  // weight select
  const bf16_t* Bm;
  int ncol0;   // weight-row base
  if (nbx < 16)      { Bm = Wq; ncol0 = nbx * 128; }
  else if (nbx < 20) { Bm = Wk; ncol0 = (nbx - 16) * 128; }
  else               { Bm = Wv; ncol0 = (nbx - 20) * 128; }

  f32x4 acc[4][4] = {};

  const int srow = tid >> 3;
  const int scol = (tid & 7) * 8;

  for (int k0 = 0; k0 < EMB; k0 += 64) {
#pragma unroll
    for (int r = 0; r < 4; ++r) {
      const int row = r * 32 + srow;
      GL2LDS16(A + (size_t)(m0 + row) * EMB + k0 + scol, As + row * 64 + scol);
    }
#pragma unroll
    for (int r = 0; r < 4; ++r) {
      const int row = r * 32 + srow;
      GL2LDS16(Bm + (size_t)(ncol0 + row) * EMB + k0 + scol, Bs + row * 64 + scol);
    }
    __syncthreads();

#pragma unroll
    for (int ks = 0; ks < 2; ++ks) {
      const int kc = ks * 32 + lq * 8;
      bf16x8 af[4], bf[4];
#pragma unroll
      for (int i = 0; i < 4; ++i)
        af[i] = *(const bf16x8*)(As + (wm + i * 16 + l15) * 64 + kc);
#pragma unroll
      for (int j = 0; j < 4; ++j)
        bf[j] = *(const bf16x8*)(Bs + (wn + j * 16 + l15) * 64 + kc);
#pragma unroll
      for (int i = 0; i < 4; ++i)
#pragma unroll
        for (int j = 0; j < 4; ++j)
          acc[i][j] = __builtin_amdgcn_mfma_f32_16x16x32_bf16(af[i], bf[j], acc[i][j], 0, 0, 0);
    }
    __syncthreads();
  }

  // C/D layout: col = lane&15, row = (lane>>4)*4 + reg
  if (nbx < 16) {          // Q: scale + row-major bf16
#pragma unroll
    for (int i = 0; i < 4; ++i) {
      const int rbase = m0 + wm + i * 16 + lq * 4;
#pragma unroll
      for (int j = 0; j < 4; ++j) {
        const int col = ncol0 + wn + j * 16 + l15;
#pragma unroll
        for (int r = 0; r < 4; ++r)
          Qb[(size_t)(rbase + r) * EMB + col] = (bf16_t)(acc[i][j][r] * qalpha);
      }
    }
  } else if (nbx < 20) {   // K: row-major bf16 into (4096,512)
#pragma unroll
    for (int i = 0; i < 4; ++i) {
      const int rbase = m0 + wm + i * 16 + lq * 4;
#pragma unroll
      for (int j = 0; j < 4; ++j) {
        const int col = ncol0 + wn + j * 16 + l15;
#pragma unroll
        for (int r = 0; r < 4; ++r)
          Kb[(size_t)(rbase + r) * KVDIM + col] = (bf16_t)acc[i][j][r];
      }
    }
  } else {                 // V: write transposed, 4 consecutive t per lane
    const int b = m0 >> 11;
    const int mloc0 = (m0 & 2047) + wm + lq * 4;
#pragma unroll
    for (int i = 0; i < 4; ++i) {
      const int mloc = mloc0 + i * 16;
#pragma unroll
      for (int j = 0; j < 4; ++j) {
        const int d = ncol0 + wn + j * 16 + l15;
        *(bf16x4*)(Vt + (size_t)(b * KVDIM + d) * T_SEQ + mloc) =
            bf16x4{(__bf16)acc[i][j][0], (__bf16)acc[i][j][1],
                   (__bf16)acc[i][j][2], (__bf16)acc[i][j][3]};
      }
    }
  }
}

// =====================================================================
// GEMM (out-projection): C(M,N) = A(M,K) @ B(N,K)^T, fp32 out.
// =====================================================================
__global__ __launch_bounds__(256, 2)
void gemm_out(const bf16_t* __restrict__ A, const bf16_t* __restrict__ Bm,
              float* __restrict__ C, int M, int N, int K)
{
  __shared__ bf16_t As[128 * 64];
  __shared__ bf16_t Bs[128 * 64];

  const int tid  = threadIdx.x;
  const int lane = tid & 63;
  const int wv   = tid >> 6;
  const int m0 = blockIdx.y * 128;
  const int n0 = blockIdx.x * 128;
  const int wm = (wv >> 1) * 64;
  const int wn = (wv & 1) * 64;
  const int l15 = lane & 15;
  const int lq  = lane >> 4;

  f32x4 acc[4][4] = {};
  const int srow = tid >> 3;
  const int scol = (tid & 7) * 8;

  for (int k0 = 0; k0 < K; k0 += 64) {
#pragma unroll
    for (int r = 0; r < 4; ++r) {
      const int row = r * 32 + srow;
      GL2LDS16(A + (size_t)(m0 + row) * K + k0 + scol, As + row * 64 + scol);
    }
#pragma unroll
    for (int r = 0; r < 4; ++r) {
      const int row = r * 32 + srow;
      GL2LDS16(Bm + (size_t)(n0 + row) * K + k0 + scol, Bs + row * 64 + scol);
    }
    __syncthreads();

#pragma unroll
    for (int ks = 0; ks < 2; ++ks) {
      const int kc = ks * 32 + lq * 8;
      bf16x8 af[4], bf[4];
#pragma unroll
      for (int i = 0; i < 4; ++i)
        af[i] = *(const bf16x8*)(As + (wm + i * 16 + l15) * 64 + kc);
#pragma unroll
      for (int j = 0; j < 4; ++j)
        bf[j] = *(const bf16x8*)(Bs + (wn + j * 16 + l15) * 64 + kc);
#pragma unroll
      for (int i = 0; i < 4; ++i)
#pragma unroll
        for (int j = 0; j < 4; ++j)
          acc[i][j] = __builtin_amdgcn_mfma_f32_16x16x32_bf16(af[i], bf[j], acc[i][j], 0, 0, 0);
    }
    __syncthreads();
  }

#pragma unroll
  for (int i = 0; i < 4; ++i) {
    const int rbase = m0 + wm + i * 16 + lq * 4;
#pragma unroll
    for (int j = 0; j < 4; ++j) {
      const int col = n0 + wn + j * 16 + l15;
#pragma unroll
      for (int r = 0; r < 4; ++r)
        C[(size_t)(rbase + r) * N + col] = acc[i][j][r];
    }
  }
}

// =====================================================================
// Flash attention, causal, GQA, no-max exp2 softmax, S^T orientation.
// q-tile 128/block: 4 waves x 2 q-groups of 16 rows; kv tile 64.
// K double-buffered (global_load_lds), V single-buffered, P per (group,wave)
// XOR-swizzled in 8B blocks. LDS = 32K + 16K + 16K = 65536 B exactly.
// K/V fragment reads are SHARED across the two q-groups (halved traffic).
// Grid (8, NH, B): block x does qt=15-x then qt=x -> 34 stage-iters each.
// =====================================================================
__global__ __launch_bounds__(256)
void attn_fwd(const bf16_t* __restrict__ Q, const bf16_t* __restrict__ Kg,
              const bf16_t* __restrict__ Vt, bf16_t* __restrict__ Y)
{
  __shared__ bf16_t Ks[2][64 * 128];   // [t][16B blk], blk = pos ^ (t&7)
  __shared__ bf16_t Vs[128 * 64];      // [d][16B blk], blk = pos ^ (d&7)
  __shared__ bf16_t Ps[2][4][16 * 64]; // [group][wave][q][kv], 8B-blk ^ (q&7)

  const int tid  = threadIdx.x;
  const int lane = tid & 63;
  const int wv   = tid >> 6;
  const int l15  = lane & 15;
  const int lq   = lane >> 4;
  const int h  = blockIdx.y;
  const int b  = blockIdx.z;
  const int hkv = h >> 2;
  const int q7 = l15 & 7;
  bf16_t* P0 = Ps[0][wv];
  bf16_t* P1 = Ps[1][wv];

  auto stageK = [&](int kt, int bufsel) {
    const int base_t = b * T_SEQ + kt * 64;
#pragma unroll
    for (int r = 0; r < 4; ++r) {
      const int c = r * 256 + tid;
      const int row = c >> 4, p = c & 15;
      const int sb = p ^ (row & 7);
      GL2LDS16(Kg + (size_t)(base_t + row) * KVDIM + hkv * HD + sb * 8,
               &Ks[bufsel][c * 8]);
    }
  };
  auto stageV = [&](int kt) {
#pragma unroll
    for (int r = 0; r < 4; ++r) {
      const int c = r * 256 + tid;
      const int row = c >> 3, p = c & 7;
      const int sb = p ^ (row & 7);
      GL2LDS16(Vt + (size_t)(b * KVDIM + hkv * HD + row) * T_SEQ + kt * 64 + sb * 8,
               &Vs[c * 8]);
    }
  };

#pragma unroll 1
  for (int ph = 0; ph < 2; ++ph) {
    const int qt = ph ? blockIdx.x : (15 - blockIdx.x);
    const int q0 = qt * 128;
    const int nkt = 2 * qt + 2;
    const int qa0 = q0 + wv * 16 + l15;       // group-0 q row
    const int qa1 = qa0 + 64;                 // group-1 q row

    // Q fragments (B-operand: n=l15=q, k=lq*8+j). Q pre-scaled.
    bf16x8 qf0[4], qf1[4];
    {
      const bf16_t* qp0 = Q + ((size_t)(b * T_SEQ + qa0) * NH + h) * HD + lq * 8;
      const bf16_t* qp1 = Q + ((size_t)(b * T_SEQ + qa1) * NH + h) * HD + lq * 8;
#pragma unroll
      for (int ds = 0; ds < 4; ++ds) {
        qf0[ds] = *(const bf16x8*)(qp0 + ds * 32);
        qf1[ds] = *(const bf16x8*)(qp1 + ds * 32);
      }
    }

    float l0 = 0.f, l1 = 0.f;
    f32x4 o0[8], o1[8];
#pragma unroll
    for (int nb = 0; nb < 8; ++nb) {
      o0[nb] = f32x4{0.f, 0.f, 0.f, 0.f};
      o1[nb] = f32x4{0.f, 0.f, 0.f, 0.f};
    }

    __syncthreads();            // prior phase fully done with LDS
    stageK(0, 0);

    for (int kt = 0; kt < nkt; ++kt) {
      const int cur = kt & 1;
      __syncthreads();          // syncA: Ks[cur] staged; Vs free
      stageV(kt);
      if (kt + 1 < nkt) stageK(kt + 1, cur ^ 1);

      const bool g0 = (kt < nkt - 1);   // group-0 skips its fully-masked tile

      // ---- S^T = K Q^T for both q-groups (K-frags read ONCE) ----
      f32x4 s0[4], s1[4];
#pragma unroll
      for (int nb = 0; nb < 4; ++nb) {
        s0[nb] = f32x4{0.f, 0.f, 0.f, 0.f};
        s1[nb] = f32x4{0.f, 0.f, 0.f, 0.f};
        const int row = nb * 16 + l15;
        const int r7  = row & 7;
#pragma unroll
        for (int ds = 0; ds < 4; ++ds) {
          const bf16x8 kf = *(const bf16x8*)&Ks[cur][row * 128 + (((ds * 4 + lq) ^ r7) * 8)];
          if (g0) s0[nb] = __builtin_amdgcn_mfma_f32_16x16x32_bf16(kf, qf0[ds], s0[nb], 0, 0, 0);
          s1[nb] = __builtin_amdgcn_mfma_f32_16x16x32_bf16(kf, qf1[ds], s1[nb], 0, 0, 0);
        }
      }

      // ---- exp2 + P writes (8B blocks, blk ^ (q&7)) ----
      if (g0) {
        const bool dia = (kt == nkt - 2);
#pragma unroll
        for (int nb = 0; nb < 4; ++nb) {
          const int kvb = kt * 64 + nb * 16 + lq * 4;
          float p0, p1, p2, p3;
          if (dia) {
            p0 = (kvb + 0 <= qa0) ? fast_exp2(s0[nb][0]) : 0.f;
            p1 = (kvb + 1 <= qa0) ? fast_exp2(s0[nb][1]) : 0.f;
            p2 = (kvb + 2 <= qa0) ? fast_exp2(s0[nb][2]) : 0.f;
            p3 = (kvb + 3 <= qa0) ? fast_exp2(s0[nb][3]) : 0.f;
          } else {
            p0 = fast_exp2(s0[nb][0]); p1 = fast_exp2(s0[nb][1]);
            p2 = fast_exp2(s0[nb][2]); p3 = fast_exp2(s0[nb][3]);
          }
          l0 += (p0 + p1) + (p2 + p3);
          *(bf16x4*)(P0 + l15 * 64 + (((nb * 4 + lq) ^ q7) << 2)) =
              bf16x4{(__bf16)p0, (__bf16)p1, (__bf16)p2, (__bf16)p3};
        }
      }
      {
        const bool dia = (kt == nkt - 1);
#pragma unroll
        for (int nb = 0; nb < 4; ++nb) {
          const int kvb = kt * 64 + nb * 16 + lq * 4;
          float p0, p1, p2, p3;
          if (dia) {
            p0 = (kvb + 0 <= qa1) ? fast_exp2(s1[nb][0]) : 0.f;
            p1 = (kvb + 1 <= qa1) ? fast_exp2(s1[nb][1]) : 0.f;
            p2 = (kvb + 2 <= qa1) ? fast_exp2(s1[nb][2]) : 0.f;
            p3 = (kvb + 3 <= qa1) ? fast_exp2(s1[nb][3]) : 0.f;
          } else {
            p0 = fast_exp2(s1[nb][0]); p1 = fast_exp2(s1[nb][1]);
            p2 = fast_exp2(s1[nb][2]); p3 = fast_exp2(s1[nb][3]);
          }
          l1 += (p0 + p1) + (p2 + p3);
          *(bf16x4*)(P1 + l15 * 64 + (((nb * 4 + lq) ^ q7) << 2)) =
              bf16x4{(__bf16)p0, (__bf16)p1, (__bf16)p2, (__bf16)p3};
        }
      }

      __syncthreads();          // syncB: Vs staged by all waves
      asm volatile("s_waitcnt lgkmcnt(0)" ::: "memory");  // P writes landed

      // ---- O^T += V^T P^T for both groups (V-frags read ONCE) ----
#pragma unroll
      for (int ks = 0; ks < 2; ++ks) {
        const int blA = ((ks * 8 + 2 * lq) ^ q7) << 2;
        const int blB = ((ks * 8 + 2 * lq + 1) ^ q7) << 2;
        const bf16x4 a0 = *(const bf16x4*)(P0 + l15 * 64 + blA);
        const bf16x4 b0 = *(const bf16x4*)(P0 + l15 * 64 + blB);
        const bf16x4 a1 = *(const bf16x4*)(P1 + l15 * 64 + blA);
        const bf16x4 b1 = *(const bf16x4*)(P1 + l15 * 64 + blB);
        const bf16x8 pf0 = __builtin_shufflevector(a0, b0, 0, 1, 2, 3, 4, 5, 6, 7);
        const bf16x8 pf1 = __builtin_shufflevector(a1, b1, 0, 1, 2, 3, 4, 5, 6, 7);
#pragma unroll
        for (int nb = 0; nb < 8; ++nb) {
          const int row = nb * 16 + l15;
          const bf16x8 vf = *(const bf16x8*)&Vs[row * 64 + (((ks * 4 + lq) ^ (row & 7)) * 8)];
          if (g0) o0[nb] = __builtin_amdgcn_mfma_f32_16x16x32_bf16(vf, pf0, o0[nb], 0, 0, 0);
          o1[nb] = __builtin_amdgcn_mfma_f32_16x16x32_bf16(vf, pf1, o1[nb], 0, 0, 0);
        }
      }
    }

    // ---- epilogue: per-group l reduce over lq, store Y ----
    {
      float lt = l0;
      lt += __shfl_xor(lt, 16);
      lt += __shfl_xor(lt, 32);
      const float inv = 1.f / lt;
      bf16_t* yp = Y + ((size_t)(b * T_SEQ + qa0) * NH + h) * HD + lq * 4;
#pragma unroll
      for (int nb = 0; nb < 8; ++nb)
        *(bf16x4*)(yp + nb * 16) = bf16x4{(__bf16)(o0[nb][0] * inv), (__bf16)(o0[nb][1] * inv),
                                          (__bf16)(o0[nb][2] * inv), (__bf16)(o0[nb][3] * inv)};
    }
    {
      float lt = l1;
      lt += __shfl_xor(lt, 16);
      lt += __shfl_xor(lt, 32);
      const float inv = 1.f / lt;
      bf16_t* yp = Y + ((size_t)(b * T_SEQ + qa1) * NH + h) * HD + lq * 4;
#pragma unroll
      for (int nb = 0; nb < 8; ++nb)
        *(bf16x4*)(yp + nb * 16) = bf16x4{(__bf16)(o1[nb][0] * inv), (__bf16)(o1[nb][1] * inv),
                                          (__bf16)(o1[nb][2] * inv), (__bf16)(o1[nb][3] * inv)};
    }
  }
}

// =====================================================================
// launch
// =====================================================================
extern "C" void kernel_launch(void* const* d_in, const int* in_sizes, int n_in,
                              void* d_out, int out_size, void* d_ws, size_t ws_size,
                              hipStream_t stream) {
  const float* x  = (const float*)d_in[0];
  const float* wq = (const float*)d_in[1];
  const float* wk = (const float*)d_in[2];
  const float* wv = (const float*)d_in[3];
  const float* wo = (const float*)d_in[4];
  float* out = (float*)d_out;

  const size_t n_x  = (size_t)MROWS * EMB;
  const size_t n_wq = (size_t)EMB * EMB;
  const size_t n_wk = (size_t)KVDIM * EMB;

  bf16_t* xb  = (bf16_t*)d_ws;
  bf16_t* wqb = xb  + n_x;
  bf16_t* wkb = wqb + n_wq;
  bf16_t* wvb = wkb + n_wk;
  bf16_t* wob = wvb + n_wk;
  bf16_t* Qb  = wob + n_wq;                  // 4096*2048
  bf16_t* Kb  = Qb + (size_t)MROWS * EMB;    // 4096*512
  bf16_t* Vtb = Kb + (size_t)MROWS * KVDIM;  // (B*512)*2048 transposed V
  bf16_t* Yb  = Vtb + (size_t)MROWS * KVDIM; // 4096*2048

  dim3 blk(256);

  cvt_all<<<dim3(18432), blk, 0, stream>>>(
      (const float4*)x, (const float4*)wq, (const float4*)wk, (const float4*)wv, (const float4*)wo,
      (bf16x4*)xb, (bf16x4*)wqb, (bf16x4*)wkb, (bf16x4*)wvb, (bf16x4*)wob);

  // Q,K,V in one dispatch; Q scaled by SCALE*log2e; V written transposed.
  const float qalpha = 0.08838834764831845f * 1.4426950408889634f;
  gemm_qkv<<<dim3(24, MROWS / 128), blk, 0, stream>>>(xb, wqb, wkb, wvb,
                                                      Qb, Kb, Vtb, qalpha);

  attn_fwd<<<dim3(8, NH, BATCH), blk, 0, stream>>>(Qb, Kb, Vtb, Yb);

  gemm_out<<<dim3(EMB / 128, MROWS / 128), blk, 0, stream>>>(Yb, wob, out, MROWS, EMB, EMB);
}